// Round 4
// baseline (348.739 us; speedup 1.0000x reference)
//
#include <hip/hip_runtime.h>

// DelayedXOR_SH_SNN: fused SNN scan, software-pipelined LDS edition.
//   x [B,T,I] f32, W1 [H,I], b1 [H], tau_m [H], W2 [O,H], b2 [O]
//   B=1024 T=2048 I=16 H=64 O=1, V_TH=1.0
// One 64-lane wave per batch element b; lane = hidden unit h (no TLP exists:
// B*H/64 = 1024 waves = 1 wave/SIMD, so all latency must hide under ILP).
// x staged global->LDS double-buffered, TRANSPOSED [i][t]; timesteps are
// processed in quads read as ds_read_b128 into two named register buffers
// (qa/qb) pipelined one quad ahead -> LDS latency hides under the previous
// quad's ~300-cycle compute block. Dot + scan are strict-order, non-fused
// scalar f32 (bit-exact vs numpy; absmax was 0.0 in rounds 2-3).

typedef float v4f_t __attribute__((ext_vector_type(4)));

constexpr int Bn = 1024;
constexpr int Tn = 2048;
constexpr int In = 16;

constexpr int CHUNK = 128;                  // timesteps per LDS buffer
constexpr int NCH = Tn / CHUNK;             // 16 chunks
constexpr int ROWP = 132;                   // dword pitch of row i (16B multiple)
constexpr int CHUNK_F4 = CHUNK * In / 4;    // 512 float4 per chunk
constexpr int F4L = CHUNK_F4 / 64;          // 8 float4 per lane staging
constexpr int QPC = CHUNK / 4;              // 32 quads per chunk

__global__ __launch_bounds__(64) void snn_fused_kernel(
    const float* __restrict__ x,
    const float* __restrict__ W1,
    const float* __restrict__ b1,
    const float* __restrict__ tau,
    const float* __restrict__ W2,
    const float* __restrict__ b2,
    float* __restrict__ out)
{
    const int b = blockIdx.x;
    const int lane = threadIdx.x;   // h index

    __shared__ __align__(16) float lds[2][In * ROWP];  // 16896 B

    // Per-lane W1 row.
    float w[In];
#pragma unroll
    for (int i = 0; i < In; ++i) w[i] = W1[lane * In + i];
    const float bias = b1[lane];

    // alpha = sigmoid(tau_m[h]) in f64, rounded once.
    const double td = (double)tau[lane];
    const float alpha = (float)(1.0 / (1.0 + exp(-td)));
    const float onem = __fsub_rn(1.0f, alpha);

    const float4* xg = (const float4*)(x + (size_t)b * (size_t)(Tn * In));

    // Transposed-commit bases: lane stores dwords d = j*256 + lane*4 + c;
    // i = d & 15, t = d >> 4 -> addr = i*ROWP + t. Banks: (4i + t) % 32
    // -> exactly 2 lanes/bank = free.
    int wbase[4];
#pragma unroll
    for (int cc = 0; cc < 4; ++cc) {
        const int d0 = lane * 4 + cc;
        wbase[cc] = (d0 & 15) * ROWP + (d0 >> 4);
    }

    float4 st[F4L];

    // Preload chunk 0 into LDS buffer 0 (transposed).
#pragma unroll
    for (int j = 0; j < F4L; ++j) st[j] = xg[j * 64 + lane];
#pragma unroll
    for (int j = 0; j < F4L; ++j) {
        lds[0][wbase[0] + j * 16] = st[j].x;
        lds[0][wbase[1] + j * 16] = st[j].y;
        lds[0][wbase[2] + j * 16] = st[j].z;
        lds[0][wbase[3] + j * 16] = st[j].w;
    }

    float v = 0.0f, s = 0.0f, acc = 0.0f, accHalf = 0.0f;

    // Two named quad buffers (never runtime-indexed -> stay in VGPRs).
    v4f_t qa[In], qb[In];

    // 4 scan steps from one quad buffer; component k = timestep within quad.
    // Strict left-assoc non-fused chain, identical to rounds 2-3 (absmax 0.0).
    auto step4 = [&](const v4f_t (&Q)[In]) {
#pragma unroll
        for (int k = 0; k < 4; ++k) {
            float ic = __fmul_rn(Q[0][k], w[0]);
#pragma unroll
            for (int i = 1; i < In; ++i)
                ic = __fadd_rn(ic, __fmul_rn(Q[i][k], w[i]));
            ic = __fadd_rn(ic, bias);

            const float t1 = __fmul_rn(alpha, v);
            const float t2 = __fmul_rn(onem, ic);
            v = __fsub_rn(__fadd_rn(t1, t2), s);
            s = (__fsub_rn(v, 1.0f) > 0.0f) ? 1.0f : 0.0f;
            acc = __fadd_rn(acc, s);   // unconditional; halved out later
        }
    };

    for (int c = 0; c < NCH; ++c) {
        if (c == NCH / 2) accHalf = acc;   // spikes counted so far = first half

        // Issue next chunk's global prefetch early (hides HBM under ~15k cyc).
        if (c + 1 < NCH) {
#pragma unroll
            for (int j = 0; j < F4L; ++j)
                st[j] = xg[(c + 1) * CHUNK_F4 + j * 64 + lane];
        }

        const float* xt = lds[c & 1];

        // Prime quad 0 into qa.
#pragma unroll
        for (int i = 0; i < In; ++i)
            qa[i] = *(const v4f_t*)&xt[i * ROWP];

#pragma unroll 1
        for (int q = 0; q < QPC; q += 2) {
            // Read quad q+1 into qb while qa computes.
#pragma unroll
            for (int i = 0; i < In; ++i)
                qb[i] = *(const v4f_t*)&xt[i * ROWP + (q + 1) * 4];

            step4(qa);   // timesteps q*4 .. q*4+3

            // Read quad q+2 into qa while qb computes.
            if (q + 2 < QPC) {
#pragma unroll
                for (int i = 0; i < In; ++i)
                    qa[i] = *(const v4f_t*)&xt[i * ROWP + (q + 2) * 4];
            }

            step4(qb);   // timesteps q*4+4 .. q*4+7
        }

        // Commit prefetched registers to the other LDS buffer (transposed).
        if (c + 1 < NCH) {
            float* dst = lds[(c & 1) ^ 1];
#pragma unroll
            for (int j = 0; j < F4L; ++j) {
                dst[wbase[0] + j * 16] = st[j].x;
                dst[wbase[1] + j * 16] = st[j].y;
                dst[wbase[2] + j * 16] = st[j].z;
                dst[wbase[3] + j * 16] = st[j].w;
            }
        }
    }

    // integrated = spikes in second half; exact small-integer subtraction.
    const float integ = __fsub_rn(acc, accHalf);

    // out[b] = sum_h integ[h] * W2[0,h] + b2[0]  (wave butterfly reduce)
    float val = __fmul_rn(integ, W2[lane]);
#pragma unroll
    for (int off = 32; off > 0; off >>= 1)
        val = __fadd_rn(val, __shfl_down(val, off));
    if (lane == 0) out[b] = __fadd_rn(val, b2[0]);
}

extern "C" void kernel_launch(void* const* d_in, const int* in_sizes, int n_in,
                              void* d_out, int out_size, void* d_ws, size_t ws_size,
                              hipStream_t stream) {
    const float* x   = (const float*)d_in[0];
    const float* W1  = (const float*)d_in[1];
    const float* b1  = (const float*)d_in[2];
    const float* tau = (const float*)d_in[3];
    const float* W2  = (const float*)d_in[4];
    const float* b2  = (const float*)d_in[5];
    float* out = (float*)d_out;

    snn_fused_kernel<<<dim3(Bn), dim3(64), 0, stream>>>(x, W1, b1, tau, W2, b2, out);
}

// Round 6
// 294.687 us; speedup vs baseline: 1.1834x; 1.1834x over previous
//
#include <hip/hip_runtime.h>

// DelayedXOR_SH_SNN: fused SNN scan — packed dual-dot + 2-deep LDS pipeline.
//   x [B,T,I] f32, W1 [H,I], b1 [H], tau_m [H], W2 [O,H], b2 [O]
//   B=1024 T=2048 I=16 H=64 O=1, V_TH=1.0
// One 64-lane wave per batch element b; lane = hidden unit h. Grid = 1024
// single-wave blocks = 1 wave/SIMD: no TLP, so latency hides under ILP only.
// x is staged global->LDS double-buffered and TRANSPOSED [i][t]; quads of 4
// timesteps are read as ds_read_b128 into two NAMED register buffers (qa/qb,
// never runtime-indexed) one quad ahead of use. The fc1 dot runs as a packed
// <2 x float> chain (v_pk_mul/v_pk_add: lo = step t, hi = step t+1) with the
// exact left-assoc per-component order of the numpy reference, contraction
// off (no fma). Scan is strict scalar f32. absmax was 0.0 in rounds 2-4.

typedef float v2f __attribute__((ext_vector_type(2)));
typedef float v4f_t __attribute__((ext_vector_type(4)));

constexpr int Bn = 1024;
constexpr int Tn = 2048;
constexpr int In = 16;

constexpr int CHUNK = 128;                  // timesteps per LDS buffer
constexpr int NCH = Tn / CHUNK;             // 16 chunks
constexpr int ROWP = 132;                   // dword pitch per i-row (16B mult)
constexpr int CHUNK_F4 = CHUNK * In / 4;    // 512 float4 per chunk
constexpr int F4L = CHUNK_F4 / 64;          // 8 float4 per lane staging
constexpr int QPC = CHUNK / 4;              // 32 quads per chunk

__global__ __launch_bounds__(64, 1) void snn_fused_kernel(
    const float* __restrict__ x,
    const float* __restrict__ W1,
    const float* __restrict__ b1,
    const float* __restrict__ tau,
    const float* __restrict__ W2,
    const float* __restrict__ b2,
    float* __restrict__ out)
{
    const int b = blockIdx.x;
    const int lane = threadIdx.x;   // h index

    __shared__ __align__(16) float lds[2][In * ROWP];  // 16896 B

    // Per-lane W1 row, duplicated into both halves for the pk ops.
    v2f w2[In];
#pragma unroll
    for (int i = 0; i < In; ++i) {
        const float wv = W1[lane * In + i];
        w2[i].x = wv; w2[i].y = wv;
    }
    const float biasf = b1[lane];
    v2f bias2; bias2.x = biasf; bias2.y = biasf;

    // alpha = sigmoid(tau_m[h]) in f64, rounded once.
    const double td = (double)tau[lane];
    const float alpha = (float)(1.0 / (1.0 + exp(-td)));
    const float onem = __fsub_rn(1.0f, alpha);

    const float4* xg = (const float4*)(x + (size_t)b * (size_t)(Tn * In));

    // Transposed-commit bases: lane stores chunk-dwords g = j*256 + lane*4+cc;
    // i = g & 15, t = g >> 4 -> addr = i*ROWP + t. 2 lanes/bank = free.
    int wbase[4];
#pragma unroll
    for (int cc = 0; cc < 4; ++cc) {
        const int g0 = lane * 4 + cc;
        wbase[cc] = (g0 & 15) * ROWP + (g0 >> 4);
    }

    float4 st[F4L];

    // Preload chunk 0 into LDS buffer 0 (transposed).
#pragma unroll
    for (int j = 0; j < F4L; ++j) st[j] = xg[j * 64 + lane];
#pragma unroll
    for (int j = 0; j < F4L; ++j) {
        lds[0][wbase[0] + j * 16] = st[j].x;
        lds[0][wbase[1] + j * 16] = st[j].y;
        lds[0][wbase[2] + j * 16] = st[j].z;
        lds[0][wbase[3] + j * 16] = st[j].w;
    }

    float v = 0.0f, s = 0.0f, acc = 0.0f, accHalf = 0.0f;

    // Two named quad buffers (compile-time indexed only -> stay in VGPRs).
    v4f_t qa[In], qb[In];

    // One scalar scan step given this step's input current.
    auto scan1 = [&](float ic) {
        const float t1 = __fmul_rn(alpha, v);
        const float t2 = __fmul_rn(onem, ic);
        v = __fsub_rn(__fadd_rn(t1, t2), s);
        // (v - 1 > 0) == (v > 1) exactly in f32 (Sterbenz on [0.5,2],
        // sign-preserving rounding outside).
        s = (v > 1.0f) ? 1.0f : 0.0f;
        acc = __fadd_rn(acc, s);   // unconditional; first half removed later
    };

    // 4 scan steps from one quad buffer: two packed dual-dots (steps 0,1 from
    // .xy; steps 2,3 from .zw), exact left-assoc order per component.
    auto step4 = [&](const v4f_t (&Q)[In]) {
#pragma clang fp contract(off)
        v2f d01 = Q[0].xy * w2[0];
        v2f d23 = Q[0].zw * w2[0];
#pragma unroll
        for (int i = 1; i < In; ++i) {
            d01 = d01 + Q[i].xy * w2[i];
            d23 = d23 + Q[i].zw * w2[i];
        }
        d01 = d01 + bias2;
        d23 = d23 + bias2;
        scan1(d01.x);
        scan1(d01.y);
        scan1(d23.x);
        scan1(d23.y);
    };

    for (int c = 0; c < NCH; ++c) {
        if (c == NCH / 2) accHalf = acc;   // spikes counted in first half

        // Issue next chunk's global prefetch early (hides HBM latency).
        if (c + 1 < NCH) {
#pragma unroll
            for (int j = 0; j < F4L; ++j)
                st[j] = xg[(c + 1) * CHUNK_F4 + j * 64 + lane];
        }

        const float* xt = lds[c & 1];

        // Prime quad 0 into qa.
#pragma unroll
        for (int i = 0; i < In; ++i)
            qa[i] = *(const v4f_t*)&xt[i * ROWP];

#pragma unroll 1
        for (int q = 0; q < QPC; q += 2) {
            // Read quad q+1 into qb while qa computes.
#pragma unroll
            for (int i = 0; i < In; ++i)
                qb[i] = *(const v4f_t*)&xt[i * ROWP + (q + 1) * 4];

            step4(qa);   // timesteps q*4 .. q*4+3

            // Read quad q+2 into qa while qb computes.
            if (q + 2 < QPC) {
#pragma unroll
                for (int i = 0; i < In; ++i)
                    qa[i] = *(const v4f_t*)&xt[i * ROWP + (q + 2) * 4];
            }

            step4(qb);   // timesteps q*4+4 .. q*4+7
        }

        // Commit prefetched registers to the other LDS buffer (transposed).
        if (c + 1 < NCH) {
            float* dst = lds[(c & 1) ^ 1];
#pragma unroll
            for (int j = 0; j < F4L; ++j) {
                dst[wbase[0] + j * 16] = st[j].x;
                dst[wbase[1] + j * 16] = st[j].y;
                dst[wbase[2] + j * 16] = st[j].z;
                dst[wbase[3] + j * 16] = st[j].w;
            }
        }
    }

    // integrated = spikes in second half; exact small-integer subtraction.
    const float integ = __fsub_rn(acc, accHalf);

    // out[b] = sum_h integ[h] * W2[0,h] + b2[0]  (wave butterfly reduce)
    float val = __fmul_rn(integ, W2[lane]);
#pragma unroll
    for (int off = 32; off > 0; off >>= 1)
        val = __fadd_rn(val, __shfl_down(val, off));
    if (lane == 0) out[b] = __fadd_rn(val, b2[0]);
}

extern "C" void kernel_launch(void* const* d_in, const int* in_sizes, int n_in,
                              void* d_out, int out_size, void* d_ws, size_t ws_size,
                              hipStream_t stream) {
    const float* x   = (const float*)d_in[0];
    const float* W1  = (const float*)d_in[1];
    const float* b1  = (const float*)d_in[2];
    const float* tau = (const float*)d_in[3];
    const float* W2  = (const float*)d_in[4];
    const float* b2  = (const float*)d_in[5];
    float* out = (float*)d_out;

    snn_fused_kernel<<<dim3(Bn), dim3(64), 0, stream>>>(x, W1, b1, tau, W2, b2, out);
}